// Round 14
// baseline (3258.655 us; speedup 1.0000x reference)
//
#include <hip/hip_runtime.h>

// PASSING numerics contract (round 5, absmax 0.00195): every conv output must
// be a strictly sequential fp32 FMA chain in (ky,kx outer, cin inner) order,
// bias added after, fp32 stores. MLP layers: per-output sequential ascending-i
// chain, +bias, lrelu. Do NOT reorder/split K, do NOT change dtype.
//
// Round 14: XCD-swizzled conv + 32KB weight slabs. R13 showed weights-in-LDS
// alone doesn't help: FETCH 180MB = 7x unique -> all 9 taps re-read input
// from L3 (600-900cyc), and 64KB LDS halved occupancy. Now: 1D grid with
// tile = (bid&7)*ceil(T/8) + (bid>>3) so each XCD (round-robin dispatch)
// owns a contiguous (n,y-band) chunk: working set ~3.4MB < 4MiB L2 -> taps
// 2..9 hit L2 (~200cyc). Weight slab halved to 32KB (cin-halves, ascending)
// -> ~4 blocks/CU. Chain order per output unchanged -> bit-identical.

#define HW2 13456   // 116*116
#define NF  12
#define NGF 4

__device__ __forceinline__ float lrelu_f(float x) { return x > 0.f ? x : 0.01f * x; }

// ---------------- build x0: (4,16,116,116) = concat(gf bcast, features) ------------
__global__ __launch_bounds__(256) void k_buildx0(const float* __restrict__ features,
                                                 const float* __restrict__ gf,
                                                 float* __restrict__ out) {
    int i = blockIdx.x * 256 + threadIdx.x;
    const int total = 4 * 16 * HW2;
    if (i >= total) return;
    int n  = i / (16 * HW2);
    int r  = i - n * (16 * HW2);
    int c  = r / HW2;
    int yx = r - c * HW2;
    float v = (c < NGF) ? gf[c] : features[(n * NF + (c - NGF)) * HW2 + yx];
    out[i] = v;
}

// ---------------- weight transpose: W[m][cin][ky][kx] -> Wt[kyx][cin][m] -----------
__global__ __launch_bounds__(256) void k_wt(const float* __restrict__ w,
                                            float* __restrict__ wt,
                                            int Cout, int Cin) {
    int i = blockIdx.x * 256 + threadIdx.x;
    int total = Cout * Cin * 9;
    if (i >= total) return;
    int m   = i / (Cin * 9);
    int r   = i - m * (Cin * 9);
    int cin = r / 9;
    int kyx = r - cin * 9;
    wt[(kyx * Cin + cin) * Cout + m] = w[i];
}

// ---------------- small transpose for kp weights: (64,64) -> [k][o] ----------------
__global__ __launch_bounds__(256) void k_wt2(const float* __restrict__ w,
                                             float* __restrict__ wt) {
    int i = blockIdx.x * 256 + threadIdx.x;  // 4096
    if (i >= 4096) return;
    int o = i >> 6, k = i & 63;
    wt[k * 64 + o] = w[i];
}

// ---------------- direct 3x3 VALID conv, XCD-swizzled, LDS weight slabs -----------
// 1D grid over T = X*Y*N tiles (tile = 32x * 4y px, 2 px/lane). Block 256thr
// = 4 waves; wave wv owns m-slice [wv*MW,(wv+1)*MW). Weights staged per
// (kyx, cin-chunk CH) as Wlds[CH][COUT] (32KB max), read via uniform
// ds_read_b128 (broadcast, in-order lgkmcnt). Inputs per-lane global_load.
template <int CIN, int COUT>
__global__ __launch_bounds__(256) void k_convx(const float* __restrict__ in,
                                               const float* __restrict__ wt,
                                               const float* __restrict__ bias,
                                               float* __restrict__ out,
                                               int H, int W, int X, int Y, int N,
                                               int T, int relu, int tout) {
    constexpr int MW = COUT / 4;
    constexpr int CH = (CIN < 64) ? CIN : 64;   // cin chunk per stage
    __shared__ float Wlds[CH * COUT];           // <= 32 KB

    // ---- XCD swizzle: round-robin dispatch -> contiguous tile chunk per XCD ----
    const int T8   = (T + 7) >> 3;
    const int bid  = blockIdx.x;
    const int tile = (bid & 7) * T8 + (bid >> 3);
    if (tile >= T) return;
    const int n  = tile / (X * Y);
    const int r0 = tile - n * X * Y;
    const int ty = r0 / X;
    const int tx = r0 - ty * X;

    const int OH = H - 2, OW = W - 2;
    const int tid = threadIdx.x, lane = tid & 63;
    const int wv  = __builtin_amdgcn_readfirstlane(tid >> 6);  // 0..3
    const int mbase = wv * MW;
    const int lx = lane & 31, lyh = lane >> 5;
    const int ox  = tx * 32 + lx;
    const int y0  = ty * 4;
    const int oyA = y0 + lyh, oyB = y0 + 2 + lyh;
    const int cx  = min(ox, OW - 1);
    const int cyA = min(oyA, OH - 1), cyB = min(oyB, OH - 1);

    const float* inb = in + (size_t)n * CIN * H * W;
    const int HW = H * W;

    float acc[MW][2];
    #pragma unroll
    for (int mi = 0; mi < MW; ++mi) { acc[mi][0] = 0.f; acc[mi][1] = 0.f; }

    // ---- K loop: kyx outer, cin-chunks then cin ascending (global order kept) ----
    for (int kyx = 0; kyx < 9; ++kyx) {
        const int ky = kyx / 3, kx = kyx - ky * 3;
        for (int h = 0; h < CIN / CH; ++h) {
            __syncthreads();   // previous slab reads done
            {
                const float* ws = wt + ((size_t)kyx * CIN + h * CH) * COUT;
                #pragma unroll
                for (int i = 0; i < CH * COUT / 1024; ++i) {
                    int idx = (i * 256 + tid) * 4;
                    *(float4*)(&Wlds[idx]) = *(const float4*)(&ws[idx]);
                }
            }
            __syncthreads();

            const float* iA = inb + (size_t)(h * CH) * HW + (cyA + ky) * W + cx + kx;
            const float* iB = inb + (size_t)(h * CH) * HW + (cyB + ky) * W + cx + kx;
            #pragma unroll 4
            for (int cin = 0; cin < CH; ++cin) {
                float vA = iA[cin * HW];     // per-lane global_load (vmcnt)
                float vB = iB[cin * HW];
                const int wbase = cin * COUT + mbase;
                #pragma unroll
                for (int j = 0; j < MW / 4; ++j) {
                    float4 w4 = *(const float4*)(&Wlds[wbase + 4 * j]);  // uniform bcast
                    acc[4*j+0][0] += w4.x * vA;  acc[4*j+0][1] += w4.x * vB;
                    acc[4*j+1][0] += w4.y * vA;  acc[4*j+1][1] += w4.y * vB;
                    acc[4*j+2][0] += w4.z * vA;  acc[4*j+2][1] += w4.z * vB;
                    acc[4*j+3][0] += w4.w * vA;  acc[4*j+3][1] += w4.w * vB;
                }
            }
        }
    }

    // ---- epilogue: 2 rows per lane, 32-lane-consecutive stores (full lines) ----
    if (ox < OW) {
        #pragma unroll
        for (int p = 0; p < 2; ++p) {
            int oy = p ? oyB : oyA;
            if (oy >= OH) continue;
            if (tout) {
                float* ob = out + (size_t)(oy * OW + ox) * COUT;
                #pragma unroll
                for (int mi = 0; mi < MW; ++mi) {
                    int m = mbase + mi;
                    float val = acc[mi][p] + bias[m];
                    if (relu) val = lrelu_f(val);
                    ob[m] = val;
                }
            } else {
                #pragma unroll
                for (int mi = 0; mi < MW; ++mi) {
                    int m = mbase + mi;
                    float val = acc[mi][p] + bias[m];
                    if (relu) val = lrelu_f(val);
                    out[(((size_t)n * COUT + m) * OH + oy) * OW + ox] = val;
                }
            }
        }
    }
}

// ---------------- max over spp: (4,128,102,102) -> (128,102,102) ----------------
__global__ __launch_bounds__(256) void k_sppmax(const float* __restrict__ in,
                                                float* __restrict__ out) {
    int i = blockIdx.x * 256 + threadIdx.x;
    const int total = 128 * 102 * 102;  // 1331712
    if (i >= total) return;
    float m = in[i];
    #pragma unroll
    for (int s = 1; s < 4; ++s) m = fmaxf(m, in[i + s * total]);
    out[i] = m;
}

// ---------------- fused per-tap MLP -> wts (921600), tile-GEMM layers ----------
__global__ __launch_bounds__(256) void k_mlp(const float* __restrict__ features,
                                             const float* __restrict__ pfeat_t,  // (9216,64)
                                             const float* __restrict__ sf_w,     // (64,12)
                                             const float* __restrict__ sf_b,
                                             const float* __restrict__ w0t,      // [k][o]
                                             const float* __restrict__ b0,
                                             const float* __restrict__ w1t,      // [k][o]
                                             const float* __restrict__ b1,
                                             const float* __restrict__ w2, const float* __restrict__ b2,
                                             float* __restrict__ wts) {
    __shared__ float vx[64][256];  // [k][tap]  64 KB
    const int t   = threadIdx.x;
    const int gid = blockIdx.x * 256 + t;  // 3600*256 = 921600 exactly
    {
        int p  = gid / 100;
        int r  = gid - p * 100;
        int s  = r / 25;
        int tp = r - s * 25;
        int dy = tp / 5;
        int dx = tp - dy * 5;
        int h  = p / 96;
        int w  = p - h * 96;

        int y = 8 + h + dy, x = 8 + w + dx;
        const float* fb = features + (size_t)(s * NF) * HW2 + (size_t)y * 116 + x;
        float f[12];
        #pragma unroll
        for (int i = 0; i < 12; ++i) f[i] = fb[i * HW2];
        f[0] += (float)(dx - 2);
        f[1] += (float)(dy - 2);

        const float* pft = pfeat_t + (size_t)p * 64;
        #pragma unroll
        for (int o = 0; o < 64; ++o) {
            float a = 0.f;
            #pragma unroll
            for (int i = 0; i < 12; ++i) a += sf_w[o * 12 + i] * f[i];
            a += sf_b[o];
            vx[o][t] = pft[o] + a;
        }
    }
    __syncthreads();

    const int lane = t & 63;
    const int og   = 16 * __builtin_amdgcn_readfirstlane(t >> 6);
    const int tl   = lane * 4;

    // ---- kp0 ----
    {
        float acc[16][4];
        #pragma unroll
        for (int j = 0; j < 16; ++j)
            #pragma unroll
            for (int c = 0; c < 4; ++c) acc[j][c] = 0.f;
        #pragma unroll 4
        for (int k = 0; k < 64; ++k) {
            float4 xv = *(const float4*)(&vx[k][tl]);
            const float* wr = w0t + k * 64 + og;
            #pragma unroll
            for (int j = 0; j < 16; ++j) {
                float wj = wr[j];
                acc[j][0] += wj * xv.x; acc[j][1] += wj * xv.y;
                acc[j][2] += wj * xv.z; acc[j][3] += wj * xv.w;
            }
        }
        __syncthreads();
        #pragma unroll
        for (int j = 0; j < 16; ++j) {
            float bj = b0[og + j];
            float4 ov;
            ov.x = lrelu_f(acc[j][0] + bj); ov.y = lrelu_f(acc[j][1] + bj);
            ov.z = lrelu_f(acc[j][2] + bj); ov.w = lrelu_f(acc[j][3] + bj);
            *(float4*)(&vx[og + j][tl]) = ov;
        }
        __syncthreads();
    }

    // ---- kp1 ----
    {
        float acc[16][4];
        #pragma unroll
        for (int j = 0; j < 16; ++j)
            #pragma unroll
            for (int c = 0; c < 4; ++c) acc[j][c] = 0.f;
        #pragma unroll 4
        for (int k = 0; k < 64; ++k) {
            float4 xv = *(const float4*)(&vx[k][tl]);
            const float* wr = w1t + k * 64 + og;
            #pragma unroll
            for (int j = 0; j < 16; ++j) {
                float wj = wr[j];
                acc[j][0] += wj * xv.x; acc[j][1] += wj * xv.y;
                acc[j][2] += wj * xv.z; acc[j][3] += wj * xv.w;
            }
        }
        __syncthreads();
        #pragma unroll
        for (int j = 0; j < 16; ++j) {
            float bj = b1[og + j];
            float4 ov;
            ov.x = lrelu_f(acc[j][0] + bj); ov.y = lrelu_f(acc[j][1] + bj);
            ov.z = lrelu_f(acc[j][2] + bj); ov.w = lrelu_f(acc[j][3] + bj);
            *(float4*)(&vx[og + j][tl]) = ov;
        }
        __syncthreads();
    }

    // ---- kp2 ----
    {
        float a = 0.f;
        #pragma unroll
        for (int i = 0; i < 64; ++i) a += w2[i] * vx[i][t];
        a += b2[0];
        wts[gid] = a;
    }
}

// ---------------- final weighted-radiance reduction -> out (3,96,96), fp32 --------
__global__ __launch_bounds__(256) void k_reduce(const float* __restrict__ wts,
                                                const float* __restrict__ radiance,
                                                float* __restrict__ out) {
    int p = blockIdx.x * 256 + threadIdx.x;  // 9216
    if (p >= 9216) return;
    int h = p / 96, w = p - h * 96;
    float sw = 0.f, un0 = 0.f, un1 = 0.f, un2 = 0.f;
    const float* wp = wts + (size_t)p * 100;
    for (int s = 0; s < 4; ++s) {
        #pragma unroll
        for (int dy = 0; dy < 5; ++dy) {
            #pragma unroll
            for (int dx = 0; dx < 5; ++dx) {
                float wv = wp[s * 25 + dy * 5 + dx];
                sw += wv;
                int y = 8 + h + dy, x = 8 + w + dx;
                const float* rb = radiance + (size_t)(s * 3) * HW2 + (size_t)y * 116 + x;
                un0 += wv * rb[0 * HW2];
                un1 += wv * rb[1 * HW2];
                un2 += wv * rb[2 * HW2];
            }
        }
    }
    float inv = 1.f / (sw + 1e-8f);
    out[0 * 9216 + p] = un0 * inv;
    out[1 * 9216 + p] = un1 * inv;
    out[2 * 9216 + p] = un2 * inv;
}

extern "C" void kernel_launch(void* const* d_in, const int* in_sizes, int n_in,
                              void* d_out, int out_size, void* d_ws, size_t ws_size,
                              hipStream_t stream) {
    const float* features = (const float*)d_in[0];
    const float* radiance = (const float*)d_in[1];
    const float* gf       = (const float*)d_in[2];
    const float* emb_w0   = (const float*)d_in[3];
    const float* emb_b0   = (const float*)d_in[4];
    const float* emb_w    = (const float*)d_in[5];
    const float* emb_b    = (const float*)d_in[6];
    const float* pf_w0    = (const float*)d_in[7];
    const float* pf_b0    = (const float*)d_in[8];
    const float* pf_w1    = (const float*)d_in[9];
    const float* pf_b1    = (const float*)d_in[10];
    const float* pf_w2    = (const float*)d_in[11];
    const float* pf_b2    = (const float*)d_in[12];
    const float* sf_w     = (const float*)d_in[13];
    const float* sf_b     = (const float*)d_in[14];
    const float* kp_w0    = (const float*)d_in[15];
    const float* kp_b0    = (const float*)d_in[16];
    const float* kp_w1    = (const float*)d_in[17];
    const float* kp_b1    = (const float*)d_in[18];
    const float* kp_w2    = (const float*)d_in[19];
    const float* kp_b2    = (const float*)d_in[20];
    float* out = (float*)d_out;

    // ---- workspace layout ----
    float* WT = (float*)d_ws;
    float* wt0  = WT;                      // conv1: 16x9x128      = 18432
    float* wtE0 = WT + 18432;              // emb i: 128x9x128     = 147456 each
    float* wtP0 = WT + 18432 + 6 * 147456; // 903168
    float* wtP1 = WT + 1050624;
    float* wtP2 = WT + 1198080;            // 64-out: 128x9x64 = 73728 (end 1271808)
    float* w0t  = WT + 1271808;            // kp0 transposed [k][o] = 4096
    float* w1t  = WT + 1275904;            // kp1 transposed        = 4096 (end 1280000)
    float* A = WT + 1280000;               // ping-pong fp32 buffers, 6653952 floats each
    float* B = A + 6653952;

    auto wtr = [&](const float* w, float* dst, int Cout, int Cin) {
        int total = Cout * Cin * 9;
        k_wt<<<dim3((total + 255) / 256), 256, 0, stream>>>(w, dst, Cout, Cin);
    };
    wtr(emb_w0, wt0, 128, 16);
    for (int i = 0; i < 6; ++i) wtr(emb_w + i * 147456, wtE0 + i * 147456, 128, 128);
    wtr(pf_w0, wtP0, 128, 128);
    wtr(pf_w1, wtP1, 128, 128);
    wtr(pf_w2, wtP2, 64, 128);
    k_wt2<<<dim3(16), 256, 0, stream>>>(kp_w0, w0t);
    k_wt2<<<dim3(16), 256, 0, stream>>>(kp_w1, w1t);

    k_buildx0<<<dim3((4 * 16 * HW2 + 255) / 256), 256, 0, stream>>>(features, gf, A);

    // conv launcher: 1D swizzled grid
    auto convT = [&](auto kern, const float* in, const float* wg, const float* bi,
                     float* o, int H, int W, int N, int relu, int tout) {
        int OH = H - 2, OW = W - 2;
        int X = (OW + 31) / 32, Y = (OH + 3) / 4;
        int T = X * Y * N;
        int nb = ((T + 7) / 8) * 8;
        kern<<<dim3(nb), 256, 0, stream>>>(in, wg, bi, o, H, W, X, Y, N, T, relu, tout);
    };

    // embedding ladder
    convT(k_convx<16, 128>, A, wt0,             emb_b0,        B, 116, 116, 4, 1, 0);
    convT(k_convx<128,128>, B, wtE0 + 0*147456, emb_b + 0*128, A, 114, 114, 4, 1, 0);
    convT(k_convx<128,128>, A, wtE0 + 1*147456, emb_b + 1*128, B, 112, 112, 4, 1, 0);
    convT(k_convx<128,128>, B, wtE0 + 2*147456, emb_b + 2*128, A, 110, 110, 4, 1, 0);
    convT(k_convx<128,128>, A, wtE0 + 3*147456, emb_b + 3*128, B, 108, 108, 4, 1, 0);
    convT(k_convx<128,128>, B, wtE0 + 4*147456, emb_b + 4*128, A, 106, 106, 4, 1, 0);
    convT(k_convx<128,128>, A, wtE0 + 5*147456, emb_b + 5*128, B, 104, 104, 4, 0, 0);

    // max over spp: B (4,128,102,102) -> A (128,102,102)
    k_sppmax<<<dim3(1331712 / 256), 256, 0, stream>>>(B, A);

    // pixel-feature convs (N=1); last one stores transposed (9216,64)
    convT(k_convx<128,128>, A, wtP0, pf_b0, B, 102, 102, 1, 1, 0);
    convT(k_convx<128,128>, B, wtP1, pf_b1, A, 100, 100, 1, 1, 0);
    convT(k_convx<128, 64>, A, wtP2, pf_b2, B, 98,  98,  1, 0, 1);

    // fused MLP: pfeat_t in B -> wts in A (921600 floats)
    k_mlp<<<dim3(3600), 256, 0, stream>>>(features, B, sf_w, sf_b,
                                          w0t, kp_b0, w1t, kp_b1, kp_w2, kp_b2, A);

    // weighted radiance -> out
    k_reduce<<<dim3(36), 256, 0, stream>>>(A, radiance, out);
}

// Round 15
// 2383.310 us; speedup vs baseline: 1.3673x; 1.3673x over previous
//
#include <hip/hip_runtime.h>

// PASSING numerics contract (round 5, absmax 0.00195): every conv output must
// be a strictly sequential fp32 FMA chain in (ky,kx outer, cin inner) order,
// bias added after, fp32 stores. MLP layers: per-output sequential ascending-i
// chain, +bias, lrelu. Do NOT reorder/split K, do NOT change dtype.
//
// Round 15: R12 conv (barrier-free, s_load weights, 32x*2y, 896 blocks,
// VALU 47%) + R14's XCD swizzle (verified: FETCH 180->41MB, L2-resident
// inputs + layer-to-layer L2 carryover). R14 regressed only because its
// 32x*4y shape gave 448 blocks (1.75/CU) — grid-capped occupancy. This
// round keeps 3.5 blocks/CU AND L2-latency inputs. Chain order unchanged.

#define HW2 13456   // 116*116
#define NF  12
#define NGF 4

__device__ __forceinline__ float lrelu_f(float x) { return x > 0.f ? x : 0.01f * x; }

// ---------------- build x0: (4,16,116,116) = concat(gf bcast, features) ------------
__global__ __launch_bounds__(256) void k_buildx0(const float* __restrict__ features,
                                                 const float* __restrict__ gf,
                                                 float* __restrict__ out) {
    int i = blockIdx.x * 256 + threadIdx.x;
    const int total = 4 * 16 * HW2;
    if (i >= total) return;
    int n  = i / (16 * HW2);
    int r  = i - n * (16 * HW2);
    int c  = r / HW2;
    int yx = r - c * HW2;
    float v = (c < NGF) ? gf[c] : features[(n * NF + (c - NGF)) * HW2 + yx];
    out[i] = v;
}

// ---------------- weight transpose: W[m][cin][ky][kx] -> Wt[kyx][cin][m] -----------
__global__ __launch_bounds__(256) void k_wt(const float* __restrict__ w,
                                            float* __restrict__ wt,
                                            int Cout, int Cin) {
    int i = blockIdx.x * 256 + threadIdx.x;
    int total = Cout * Cin * 9;
    if (i >= total) return;
    int m   = i / (Cin * 9);
    int r   = i - m * (Cin * 9);
    int cin = r / 9;
    int kyx = r - cin * 9;
    wt[(kyx * Cin + cin) * Cout + m] = w[i];
}

// ---------------- small transpose for kp weights: (64,64) -> [k][o] ----------------
__global__ __launch_bounds__(256) void k_wt2(const float* __restrict__ w,
                                             float* __restrict__ wt) {
    int i = blockIdx.x * 256 + threadIdx.x;  // 4096
    if (i >= 4096) return;
    int o = i >> 6, k = i & 63;
    wt[k * 64 + o] = w[i];
}

// ---------------- direct 3x3 VALID conv, swizzled 1D grid, order-preserving --------
// Tile = 32x * 2y px, 1 px/lane (lx=lane&31, lyh=lane>>5). Block 256thr =
// 4 waves; wave wv owns m-slice [wv*MW,(wv+1)*MW), MW=COUT/4. Weights via
// wave-uniform s_load from wt[kyx][cin][m]; inputs per-lane global_load
// (vmcnt, L2-resident via swizzle). Zero barriers. Stores: full 128B lines.
template <int CIN, int COUT>
__global__ __launch_bounds__(256) void k_convs(const float* __restrict__ in,
                                               const float* __restrict__ wt,
                                               const float* __restrict__ bias,
                                               float* __restrict__ out,
                                               int H, int W, int X, int Y, int N,
                                               int T, int relu, int tout) {
    constexpr int MW = COUT / 4;

    // ---- XCD swizzle: round-robin dispatch -> contiguous tile chunk per XCD ----
    const int T8   = (T + 7) >> 3;
    const int bid  = blockIdx.x;
    const int tile = (bid & 7) * T8 + (bid >> 3);
    if (tile >= T) return;
    const int n  = tile / (X * Y);
    const int r0 = tile - n * X * Y;
    const int ty = r0 / X;
    const int tx = r0 - ty * X;

    const int OH = H - 2, OW = W - 2;
    const int tid = threadIdx.x, lane = tid & 63;
    const int wv  = __builtin_amdgcn_readfirstlane(tid >> 6);  // 0..3
    const int mbase = wv * MW;
    const int lx = lane & 31, lyh = lane >> 5;
    const int ox = tx * 32 + lx;
    const int oy = ty * 2 + lyh;                  // OH even for all layers
    const int cx = min(ox, OW - 1);               // clamp (clamped lanes never store)

    const float* inb = in + (size_t)n * CIN * H * W;
    const int HW = H * W;

    float acc[MW];
    #pragma unroll
    for (int mi = 0; mi < MW; ++mi) acc[mi] = 0.f;

    // ---- K loop: ky,kx outer, cin inner ascending (REQUIRED order) ----
    #pragma unroll
    for (int ky = 0; ky < 3; ++ky) {
        #pragma unroll
        for (int kx = 0; kx < 3; ++kx) {
            const float* ia = inb + (oy + ky) * W + cx + kx;
            const float* wr = wt + (size_t)((ky * 3 + kx) * CIN) * COUT + mbase;
            #pragma unroll 8
            for (int cin = 0; cin < CIN; ++cin) {
                float v = ia[cin * HW];             // vector load (vmcnt, L2-hit)
                const float* w = wr + cin * COUT;   // uniform -> s_load
                #pragma unroll
                for (int mi = 0; mi < MW; ++mi)
                    acc[mi] += w[mi] * v;
            }
        }
    }

    // ---- epilogue ----
    if (ox < OW) {
        if (tout) {
            float* ob = out + (size_t)(oy * OW + ox) * COUT;
            #pragma unroll
            for (int mi = 0; mi < MW; ++mi) {
                int m = mbase + mi;
                float val = acc[mi] + bias[m];
                if (relu) val = lrelu_f(val);
                ob[m] = val;
            }
        } else {
            #pragma unroll
            for (int mi = 0; mi < MW; ++mi) {
                int m = mbase + mi;
                float val = acc[mi] + bias[m];
                if (relu) val = lrelu_f(val);
                out[(((size_t)n * COUT + m) * OH + oy) * OW + ox] = val;
            }
        }
    }
}

// ---------------- max over spp: (4,128,102,102) -> (128,102,102) ----------------
__global__ __launch_bounds__(256) void k_sppmax(const float* __restrict__ in,
                                                float* __restrict__ out) {
    int i = blockIdx.x * 256 + threadIdx.x;
    const int total = 128 * 102 * 102;  // 1331712
    if (i >= total) return;
    float m = in[i];
    #pragma unroll
    for (int s = 1; s < 4; ++s) m = fmaxf(m, in[i + s * total]);
    out[i] = m;
}

// ---------------- fused per-tap MLP -> wts (921600), tile-GEMM layers ----------
__global__ __launch_bounds__(256) void k_mlp(const float* __restrict__ features,
                                             const float* __restrict__ pfeat_t,  // (9216,64)
                                             const float* __restrict__ sf_w,     // (64,12)
                                             const float* __restrict__ sf_b,
                                             const float* __restrict__ w0t,      // [k][o]
                                             const float* __restrict__ b0,
                                             const float* __restrict__ w1t,      // [k][o]
                                             const float* __restrict__ b1,
                                             const float* __restrict__ w2, const float* __restrict__ b2,
                                             float* __restrict__ wts) {
    __shared__ float vx[64][256];  // [k][tap]  64 KB
    const int t   = threadIdx.x;
    const int gid = blockIdx.x * 256 + t;  // 3600*256 = 921600 exactly
    {
        int p  = gid / 100;
        int r  = gid - p * 100;
        int s  = r / 25;
        int tp = r - s * 25;
        int dy = tp / 5;
        int dx = tp - dy * 5;
        int h  = p / 96;
        int w  = p - h * 96;

        int y = 8 + h + dy, x = 8 + w + dx;
        const float* fb = features + (size_t)(s * NF) * HW2 + (size_t)y * 116 + x;
        float f[12];
        #pragma unroll
        for (int i = 0; i < 12; ++i) f[i] = fb[i * HW2];
        f[0] += (float)(dx - 2);
        f[1] += (float)(dy - 2);

        const float* pft = pfeat_t + (size_t)p * 64;
        #pragma unroll
        for (int o = 0; o < 64; ++o) {
            float a = 0.f;
            #pragma unroll
            for (int i = 0; i < 12; ++i) a += sf_w[o * 12 + i] * f[i];
            a += sf_b[o];
            vx[o][t] = pft[o] + a;
        }
    }
    __syncthreads();

    const int lane = t & 63;
    const int og   = 16 * __builtin_amdgcn_readfirstlane(t >> 6);
    const int tl   = lane * 4;

    // ---- kp0 ----
    {
        float acc[16][4];
        #pragma unroll
        for (int j = 0; j < 16; ++j)
            #pragma unroll
            for (int c = 0; c < 4; ++c) acc[j][c] = 0.f;
        #pragma unroll 4
        for (int k = 0; k < 64; ++k) {
            float4 xv = *(const float4*)(&vx[k][tl]);
            const float* wr = w0t + k * 64 + og;
            #pragma unroll
            for (int j = 0; j < 16; ++j) {
                float wj = wr[j];
                acc[j][0] += wj * xv.x; acc[j][1] += wj * xv.y;
                acc[j][2] += wj * xv.z; acc[j][3] += wj * xv.w;
            }
        }
        __syncthreads();
        #pragma unroll
        for (int j = 0; j < 16; ++j) {
            float bj = b0[og + j];
            float4 ov;
            ov.x = lrelu_f(acc[j][0] + bj); ov.y = lrelu_f(acc[j][1] + bj);
            ov.z = lrelu_f(acc[j][2] + bj); ov.w = lrelu_f(acc[j][3] + bj);
            *(float4*)(&vx[og + j][tl]) = ov;
        }
        __syncthreads();
    }

    // ---- kp1 ----
    {
        float acc[16][4];
        #pragma unroll
        for (int j = 0; j < 16; ++j)
            #pragma unroll
            for (int c = 0; c < 4; ++c) acc[j][c] = 0.f;
        #pragma unroll 4
        for (int k = 0; k < 64; ++k) {
            float4 xv = *(const float4*)(&vx[k][tl]);
            const float* wr = w1t + k * 64 + og;
            #pragma unroll
            for (int j = 0; j < 16; ++j) {
                float wj = wr[j];
                acc[j][0] += wj * xv.x; acc[j][1] += wj * xv.y;
                acc[j][2] += wj * xv.z; acc[j][3] += wj * xv.w;
            }
        }
        __syncthreads();
        #pragma unroll
        for (int j = 0; j < 16; ++j) {
            float bj = b1[og + j];
            float4 ov;
            ov.x = lrelu_f(acc[j][0] + bj); ov.y = lrelu_f(acc[j][1] + bj);
            ov.z = lrelu_f(acc[j][2] + bj); ov.w = lrelu_f(acc[j][3] + bj);
            *(float4*)(&vx[og + j][tl]) = ov;
        }
        __syncthreads();
    }

    // ---- kp2 ----
    {
        float a = 0.f;
        #pragma unroll
        for (int i = 0; i < 64; ++i) a += w2[i] * vx[i][t];
        a += b2[0];
        wts[gid] = a;
    }
}

// ---------------- final weighted-radiance reduction -> out (3,96,96), fp32 --------
__global__ __launch_bounds__(256) void k_reduce(const float* __restrict__ wts,
                                                const float* __restrict__ radiance,
                                                float* __restrict__ out) {
    int p = blockIdx.x * 256 + threadIdx.x;  // 9216
    if (p >= 9216) return;
    int h = p / 96, w = p - h * 96;
    float sw = 0.f, un0 = 0.f, un1 = 0.f, un2 = 0.f;
    const float* wp = wts + (size_t)p * 100;
    for (int s = 0; s < 4; ++s) {
        #pragma unroll
        for (int dy = 0; dy < 5; ++dy) {
            #pragma unroll
            for (int dx = 0; dx < 5; ++dx) {
                float wv = wp[s * 25 + dy * 5 + dx];
                sw += wv;
                int y = 8 + h + dy, x = 8 + w + dx;
                const float* rb = radiance + (size_t)(s * 3) * HW2 + (size_t)y * 116 + x;
                un0 += wv * rb[0 * HW2];
                un1 += wv * rb[1 * HW2];
                un2 += wv * rb[2 * HW2];
            }
        }
    }
    float inv = 1.f / (sw + 1e-8f);
    out[0 * 9216 + p] = un0 * inv;
    out[1 * 9216 + p] = un1 * inv;
    out[2 * 9216 + p] = un2 * inv;
}

extern "C" void kernel_launch(void* const* d_in, const int* in_sizes, int n_in,
                              void* d_out, int out_size, void* d_ws, size_t ws_size,
                              hipStream_t stream) {
    const float* features = (const float*)d_in[0];
    const float* radiance = (const float*)d_in[1];
    const float* gf       = (const float*)d_in[2];
    const float* emb_w0   = (const float*)d_in[3];
    const float* emb_b0   = (const float*)d_in[4];
    const float* emb_w    = (const float*)d_in[5];
    const float* emb_b    = (const float*)d_in[6];
    const float* pf_w0    = (const float*)d_in[7];
    const float* pf_b0    = (const float*)d_in[8];
    const float* pf_w1    = (const float*)d_in[9];
    const float* pf_b1    = (const float*)d_in[10];
    const float* pf_w2    = (const float*)d_in[11];
    const float* pf_b2    = (const float*)d_in[12];
    const float* sf_w     = (const float*)d_in[13];
    const float* sf_b     = (const float*)d_in[14];
    const float* kp_w0    = (const float*)d_in[15];
    const float* kp_b0    = (const float*)d_in[16];
    const float* kp_w1    = (const float*)d_in[17];
    const float* kp_b1    = (const float*)d_in[18];
    const float* kp_w2    = (const float*)d_in[19];
    const float* kp_b2    = (const float*)d_in[20];
    float* out = (float*)d_out;

    // ---- workspace layout ----
    float* WT = (float*)d_ws;
    float* wt0  = WT;                      // conv1: 16x9x128      = 18432
    float* wtE0 = WT + 18432;              // emb i: 128x9x128     = 147456 each
    float* wtP0 = WT + 18432 + 6 * 147456; // 903168
    float* wtP1 = WT + 1050624;
    float* wtP2 = WT + 1198080;            // 64-out: 128x9x64 = 73728 (end 1271808)
    float* w0t  = WT + 1271808;            // kp0 transposed [k][o] = 4096
    float* w1t  = WT + 1275904;            // kp1 transposed        = 4096 (end 1280000)
    float* A = WT + 1280000;               // ping-pong fp32 buffers, 6653952 floats each
    float* B = A + 6653952;

    auto wtr = [&](const float* w, float* dst, int Cout, int Cin) {
        int total = Cout * Cin * 9;
        k_wt<<<dim3((total + 255) / 256), 256, 0, stream>>>(w, dst, Cout, Cin);
    };
    wtr(emb_w0, wt0, 128, 16);
    for (int i = 0; i < 6; ++i) wtr(emb_w + i * 147456, wtE0 + i * 147456, 128, 128);
    wtr(pf_w0, wtP0, 128, 128);
    wtr(pf_w1, wtP1, 128, 128);
    wtr(pf_w2, wtP2, 64, 128);
    k_wt2<<<dim3(16), 256, 0, stream>>>(kp_w0, w0t);
    k_wt2<<<dim3(16), 256, 0, stream>>>(kp_w1, w1t);

    k_buildx0<<<dim3((4 * 16 * HW2 + 255) / 256), 256, 0, stream>>>(features, gf, A);

    // conv launcher: 1D swizzled grid over 32x*2y tiles
    auto convT = [&](auto kern, const float* in, const float* wg, const float* bi,
                     float* o, int H, int W, int N, int relu, int tout) {
        int OH = H - 2, OW = W - 2;
        int X = (OW + 31) / 32, Y = OH / 2;   // OH even for all layers
        int T = X * Y * N;
        int nb = ((T + 7) / 8) * 8;
        kern<<<dim3(nb), 256, 0, stream>>>(in, wg, bi, o, H, W, X, Y, N, T, relu, tout);
    };

    // embedding ladder
    convT(k_convs<16, 128>, A, wt0,             emb_b0,        B, 116, 116, 4, 1, 0);
    convT(k_convs<128,128>, B, wtE0 + 0*147456, emb_b + 0*128, A, 114, 114, 4, 1, 0);
    convT(k_convs<128,128>, A, wtE0 + 1*147456, emb_b + 1*128, B, 112, 112, 4, 1, 0);
    convT(k_convs<128,128>, B, wtE0 + 2*147456, emb_b + 2*128, A, 110, 110, 4, 1, 0);
    convT(k_convs<128,128>, A, wtE0 + 3*147456, emb_b + 3*128, B, 108, 108, 4, 1, 0);
    convT(k_convs<128,128>, B, wtE0 + 4*147456, emb_b + 4*128, A, 106, 106, 4, 1, 0);
    convT(k_convs<128,128>, A, wtE0 + 5*147456, emb_b + 5*128, B, 104, 104, 4, 0, 0);

    // max over spp: B (4,128,102,102) -> A (128,102,102)
    k_sppmax<<<dim3(1331712 / 256), 256, 0, stream>>>(B, A);

    // pixel-feature convs (N=1); last one stores transposed (9216,64)
    convT(k_convs<128,128>, A, wtP0, pf_b0, B, 102, 102, 1, 1, 0);
    convT(k_convs<128,128>, B, wtP1, pf_b1, A, 100, 100, 1, 1, 0);
    convT(k_convs<128, 64>, A, wtP2, pf_b2, B, 98,  98,  1, 0, 1);

    // fused MLP: pfeat_t in B -> wts in A (921600 floats)
    k_mlp<<<dim3(3600), 256, 0, stream>>>(features, B, sf_w, sf_b,
                                          w0t, kp_b0, w1t, kp_b1, kp_w2, kp_b2, A);

    // weighted radiance -> out
    k_reduce<<<dim3(36), 256, 0, stream>>>(A, radiance, out);
}